// Round 3
// baseline (442.023 us; speedup 1.0000x reference)
//
#include <hip/hip_runtime.h>
#include <math.h>

#define WL     256
#define HOP    128
#define NW     239      // (30720 - 256)/128 + 1
#define NBINS  129
#define NSAMP  30720
#define NROWS  (64*23)  // 1472

// One 64-thread wave per frame. 128-pt complex FFT in LDS (radix-2 DIF,
// natural-in / bit-reversed-out), then real-FFT untangle to 129 bins.
__global__ __launch_bounds__(64) void stft_kernel(const float* __restrict__ sig,
                                                  float* __restrict__ out) {
    const int t   = threadIdx.x;           // 0..63
    const int bid = blockIdx.x;            // row*NW + w
    const int row = bid / NW;
    const int w   = bid - row * NW;
    const float* __restrict__ src = sig + (size_t)row * NSAMP + (size_t)w * HOP;

    __shared__ float re[128], im[128];
    __shared__ float twc[132], tws[132];   // W_256^k = (twc[k], tws[k]), k=0..128

    // ---- twiddle table: W_256^k = exp(-2*pi*i*k/256) = exp(-i*pi*k/128)
    for (int k = t; k <= 128; k += 64) {
        float s, c;
        sincospif((float)k * (1.0f / 128.0f), &s, &c);
        twc[k] = c;
        tws[k] = -s;                       // sine of the NEGATIVE angle
    }

    // ---- load + Hann window + pack real->complex (c[n] = x[2n] + i*x[2n+1])
    #pragma unroll
    for (int q = 0; q < 4; ++q) {
        int sidx = t + 64 * q;             // 0..255, coalesced per 64-lane step
        float v = src[sidx];
        // np.hanning(256): 0.5 - 0.5*cos(2*pi*n/255)
        float wnd = 0.5f - 0.5f * cospif(2.0f * (float)sidx * (1.0f / 255.0f));
        v *= wnd;
        if (sidx & 1) im[sidx >> 1] = v;
        else          re[sidx >> 1] = v;
    }
    __syncthreads();

    // ---- 128-pt complex FFT: radix-2 DIF, 7 stages, 64 butterflies/stage
    #pragma unroll
    for (int lm = 7; lm >= 1; --lm) {      // m = 1<<lm : 128,64,...,2
        const int half = 1 << (lm - 1);
        const int j    = t & (half - 1);
        const int i0   = ((t >> (lm - 1)) << lm) + j;
        const int i1   = i0 + half;
        const int tw   = j << (8 - lm);    // W_m^j == W_256^(j*256/m)
        float ar = re[i0], ai = im[i0];
        float br = re[i1], bi = im[i1];
        float c = twc[tw], s = tws[tw];
        float tr = ar - br, ti = ai - bi;
        re[i0] = ar + br;
        im[i0] = ai + bi;
        re[i1] = tr * c - ti * s;
        im[i1] = tr * s + ti * c;
        __syncthreads();
    }

    // ---- untangle rfft: Z[k] lives at bit-reversed index; emit 129 log-mags
    float* __restrict__ o = out + (size_t)bid * NBINS;
    #pragma unroll
    for (int q = 0; q < 2; ++q) {
        int k  = t + 64 * q;                                   // 0..127
        int pk = (int)(__brev((unsigned)(k & 127)) >> 25);
        int pm = (int)(__brev((unsigned)((128 - k) & 127)) >> 25);
        float zkr = re[pk], zki = im[pk];
        float zmr = re[pm], zmi = im[pm];
        float er  = 0.5f * (zkr + zmr);
        float ei  = 0.5f * (zki - zmi);
        float orr = 0.5f * (zki + zmi);
        float oi  = -0.5f * (zkr - zmr);
        float c = twc[k], s = tws[k];
        float Xr = er + c * orr - s * oi;
        float Xi = ei + c * oi + s * orr;
        float mag = sqrtf(Xr * Xr + Xi * Xi);
        o[k] = logf(mag + 1e-8f) * 10.0f;
    }
    if (t == 0) {
        // k = 128: X = Re(Z0) - Im(Z0), imag = 0
        float Xr = re[0] - im[0];
        o[128] = logf(fabsf(Xr) + 1e-8f) * 10.0f;
    }
}

extern "C" void kernel_launch(void* const* d_in, const int* in_sizes, int n_in,
                              void* d_out, int out_size, void* d_ws, size_t ws_size,
                              hipStream_t stream) {
    const float* sig = (const float*)d_in[0];
    float* out = (float*)d_out;
    (void)in_sizes; (void)n_in; (void)out_size; (void)d_ws; (void)ws_size;
    const int nblocks = NROWS * NW;        // 351,808 frames
    stft_kernel<<<dim3(nblocks), dim3(64), 0, stream>>>(sig, out);
}